// Round 2
// baseline (49.568 us; speedup 1.0000x reference)
//
#include <hip/hip_runtime.h>

#define TPB 256
#define ROWLEN 16000          // T
#define NROWS 1280            // B*C
#define NCHUNK 250            // active scan threads (250 * 64 = 16000)

typedef float f32x4 __attribute__((ext_vector_type(4)));

__global__ __launch_bounds__(TPB) void ema_kernel(const float* __restrict__ x,
                                                  const float* __restrict__ wts,
                                                  float* __restrict__ y) {
  __shared__ float S[TPB];                // scan array only — 1 KB LDS
  const int row = blockIdx.x;             // 0..1279 (row = b*80 + c)
  const int c   = row % 80;
  const int tid = threadIdx.x;

  const float* __restrict__ xr = x + (size_t)row * ROWLEN;
  float* __restrict__ yr       = y + (size_t)row * ROWLEN;

  float w = wts[c];
  w = fminf(fmaxf(w, 0.f), 1.f);
  const float d = 1.f - w;

  // ---- load chunk direct to regs + local decayed contribution L ----
  f32x4 xv[16];
  float L = 0.f;
  if (tid < NCHUNK) {
    const f32x4* __restrict__ src = (const f32x4*)xr + (size_t)tid * 16;
#pragma unroll
    for (int k = 0; k < 16; ++k) xv[k] = src[k];
#pragma unroll
    for (int k = 0; k < 16; ++k)
#pragma unroll
      for (int j = 0; j < 4; ++j)
        L = w * xv[k][j] + d * L;
  }
  const float init = xr[0];               // uniform scalar load (L1/L3 hit)

  // chunk decay D = d^64 via 6 squarings
  float D = d * d; D = D * D; D = D * D; D = D * D; D = D * D; D = D * D;

  // ---- block scan: S[t] = L_t + D*S[t-1] (decayed inclusive, in-place H-S) ----
  float s = (tid < NCHUNK) ? L : 0.f;
  S[tid] = s;
  __syncthreads();
  float Dp = D;
  for (int step = 1; step < TPB; step <<= 1) {
    float add = (tid >= step) ? S[tid - step] : 0.f;
    __syncthreads();
    s = s + Dp * add;
    S[tid] = s;
    Dp = Dp * Dp;
    __syncthreads();
  }

  // ---- replay exact sequential recurrence per chunk, store direct ----
  if (tid < NCHUNK) {
    float acc = powf(D, (float)tid) * init;     // D^tid * init
    if (tid > 0) acc += S[tid - 1];
    f32x4* __restrict__ dst = (f32x4*)yr + (size_t)tid * 16;
#pragma unroll
    for (int k = 0; k < 16; ++k) {
      f32x4 yv;
#pragma unroll
      for (int j = 0; j < 4; ++j) {
        acc = w * xv[k][j] + d * acc;           // same op order as reference
        yv[j] = acc;
      }
      dst[k] = yv;
    }
  }
}

extern "C" void kernel_launch(void* const* d_in, const int* in_sizes, int n_in,
                              void* d_out, int out_size, void* d_ws, size_t ws_size,
                              hipStream_t stream) {
  const float* x   = (const float*)d_in[0];
  const float* wts = (const float*)d_in[1];
  float* y         = (float*)d_out;
  ema_kernel<<<NROWS, TPB, 0, stream>>>(x, wts, y);
}

// Round 3
// 31.199 us; speedup vs baseline: 1.5888x; 1.5888x over previous
//
#include <hip/hip_runtime.h>

#define ROWLEN 16000
#define NROWS  1280
// 64 segments of 256 floats: 62 full + seg62 = 128-float tail + seg63 = pad

typedef float f32x4 __attribute__((ext_vector_type(4)));

__global__ __launch_bounds__(64) void ema_kernel(const float* __restrict__ x,
                                                 const float* __restrict__ wts,
                                                 float* __restrict__ y) {
  const int row  = blockIdx.x;           // one wave per row
  const int lane = threadIdx.x;          // 0..63
  const float* __restrict__ xr = x + (size_t)row * ROWLEN;
  float*       __restrict__ yr = y + (size_t)row * ROWLEN;

  float w = wts[row % 80];
  w = fminf(fmaxf(w, 0.f), 1.f);
  const float d = 1.f - w;

  // per-step scan decays: D4 = d^4, squared each H-S step
  const float d2  = d * d;
  const float D4  = d2 * d2;
  const float Dp0 = D4;
  const float Dp1 = Dp0 * Dp0;
  const float Dp2 = Dp1 * Dp1;
  const float Dp3 = Dp2 * Dp2;
  const float Dp4 = Dp3 * Dp3;
  const float Dp5 = Dp4 * Dp4;
  const float D256 = Dp5 * Dp5;          // D4^64 = d^256 (segment decay)

  // Dlane = D4^lane via binary expansion
  float Dlane = 1.f;
  {
    float m = D4;
    Dlane *= (lane & 1)  ? m : 1.f; m *= m;
    Dlane *= (lane & 2)  ? m : 1.f; m *= m;
    Dlane *= (lane & 4)  ? m : 1.f; m *= m;
    Dlane *= (lane & 8)  ? m : 1.f; m *= m;
    Dlane *= (lane & 16) ? m : 1.f; m *= m;
    Dlane *= (lane & 32) ? m : 1.f;
  }

  float carry = xr[0];                   // reference: acc starts at x[row,0]

  // register prefetch, depth 8 (segs 0..7 fully in-bounds: max off 2044 < 16000)
  f32x4 pre[8];
#pragma unroll
  for (int k = 0; k < 8; ++k)
    pre[k] = *(const f32x4*)(xr + k * 256 + lane * 4);

  for (int g = 0; g < 8; ++g) {
#pragma unroll
    for (int k = 0; k < 8; ++k) {
      const int s = g * 8 + k;
      const f32x4 xv = pre[k];

      // issue prefetch for segment s+8 (clamped address for pad/tail region)
      if (g < 7) {
        int off = (s + 8) * 256 + lane * 4;
        off = off > (ROWLEN - 4) ? (ROWLEN - 4) : off;
        pre[k] = *(const f32x4*)(xr + off);
      }

      // ---- local decayed scan from 0 over lane's 4 elements ----
      float L;
      L = w * xv[0];
      L = w * xv[1] + d * L;
      L = w * xv[2] + d * L;
      L = w * xv[3] + d * L;

      // ---- 6-step decayed Hillis-Steele inclusive scan across 64 lanes ----
      float sc = L, u;
      u = __shfl_up(sc, 1);  sc += (lane >= 1)  ? Dp0 * u : 0.f;
      u = __shfl_up(sc, 2);  sc += (lane >= 2)  ? Dp1 * u : 0.f;
      u = __shfl_up(sc, 4);  sc += (lane >= 4)  ? Dp2 * u : 0.f;
      u = __shfl_up(sc, 8);  sc += (lane >= 8)  ? Dp3 * u : 0.f;
      u = __shfl_up(sc, 16); sc += (lane >= 16) ? Dp4 * u : 0.f;
      u = __shfl_up(sc, 32); sc += (lane >= 32) ? Dp5 * u : 0.f;

      // exclusive prefix + carry fold: start state for this lane's replay
      float e = __shfl_up(sc, 1);
      e = (lane > 0) ? e : 0.f;
      float acc = e + Dlane * carry;

      // ---- replay: exact reference op order within the lane's 4 elements ----
      f32x4 yv;
      acc = w * xv[0] + d * acc; yv[0] = acc;
      acc = w * xv[1] + d * acc; yv[1] = acc;
      acc = w * xv[2] + d * acc; yv[2] = acc;
      acc = w * xv[3] + d * acc; yv[3] = acc;

      // ---- coalesced store (guard tail/pad) ----
      if (s < 62) {
        *(f32x4*)(yr + s * 256 + lane * 4) = yv;
      } else if (s == 62) {
        if (lane < 32) *(f32x4*)(yr + s * 256 + lane * 4) = yv;
      }

      // ---- carry across segments (garbage after seg 62 is never used) ----
      float s63 = __shfl(sc, 63);
      carry = s63 + D256 * carry;
    }
  }
}

extern "C" void kernel_launch(void* const* d_in, const int* in_sizes, int n_in,
                              void* d_out, int out_size, void* d_ws, size_t ws_size,
                              hipStream_t stream) {
  const float* x   = (const float*)d_in[0];
  const float* wts = (const float*)d_in[1];
  float* y         = (float*)d_out;
  ema_kernel<<<NROWS, 64, 0, stream>>>(x, wts, y);
}

// Round 4
// 29.692 us; speedup vs baseline: 1.6694x; 1.0508x over previous
//
#include <hip/hip_runtime.h>

#define ROWLEN 16000
#define NROWS  1280

typedef float f32x4 __attribute__((ext_vector_type(4)));

// DPP helper: returns permuted value, 0 in masked-off rows / out-of-bound lanes
template<int CTRL, int RMASK>
__device__ __forceinline__ float dppf(float v) {
  int r = __builtin_amdgcn_update_dpp(0, __builtin_bit_cast(int, v),
                                      CTRL, RMASK, 0xF, true);
  return __builtin_bit_cast(float, r);
}

__global__ __launch_bounds__(64) void ema_kernel(const float* __restrict__ x,
                                                 const float* __restrict__ wts,
                                                 float* __restrict__ y) {
  const int row  = blockIdx.x >> 1;     // 2 waves per row
  const int half = blockIdx.x & 1;
  const int lane = threadIdx.x;
  const float* __restrict__ xr = x + (size_t)row * ROWLEN;
  float*       __restrict__ yr = y + (size_t)row * ROWLEN;

  float w = wts[row % 80];
  w = fminf(fmaxf(w, 0.f), 1.f);
  const float d = 1.f - w;

  const float d2 = d * d;
  const float D4 = d2 * d2;        // per-lane-chunk decay (4 elems)
  const float W1 = D4;
  const float W2 = W1 * W1;
  const float W4 = W2 * W2;
  const float W8 = W4 * W4;
  const float D64  = W8 * W8;      // D4^16
  const float D128 = D64 * D64;
  const float D256 = D128 * D128;  // d^256 — per-segment decay

  // per-lane powers of D4 via binary expansion
  float m = D4, p15 = 1.f;
  p15 *= (lane & 1) ? m : 1.f; m *= m;
  p15 *= (lane & 2) ? m : 1.f; m *= m;
  p15 *= (lane & 4) ? m : 1.f; m *= m;
  p15 *= (lane & 8) ? m : 1.f; m *= m;                        // m = D4^16
  const float p31   = p15 * ((lane & 16) ? m : 1.f); m *= m;  // m = D4^32
  const float Dlane = p31 * ((lane & 32) ? m : 1.f);          // D4^lane
  const float F1 = D4 * p15;       // D4^((lane&15)+1)  — row_bcast15 fold
  const float F2 = D4 * p31;       // D4^((lane&31)+1)  — row_bcast31 fold

  // half 0: segs 0..31 (store all).  half 1: segs 31..62 (seg 31 = halo, no store)
  const int s_begin    = half ? 31 : 0;
  const int store_from = half ? 32 : 0;
  float carry = half ? 0.f : xr[0];

  // depth-16 register prefetch (all initial segs fully in-bounds)
  f32x4 pre[16];
#pragma unroll
  for (int k = 0; k < 16; ++k)
    pre[k] = *(const f32x4*)(xr + (s_begin + k) * 256 + lane * 4);

  for (int g = 0; g < 2; ++g) {
#pragma unroll
    for (int k = 0; k < 16; ++k) {
      const int s = s_begin + g * 16 + k;
      const f32x4 xv = pre[k];
      if (g == 0) {                 // prefetch second group (clamped for seg 62/63 tail)
        int off = (s + 16) * 256 + lane * 4;
        off = off > (ROWLEN - 4) ? (ROWLEN - 4) : off;
        pre[k] = *(const f32x4*)(xr + off);
      }

      // local decayed contribution over the lane's 4 elements (init 0)
      float L;
      L = w * xv[0];
      L = w * xv[1] + d * L;
      L = w * xv[2] + d * L;
      L = w * xv[3] + d * L;

      // decayed inclusive scan across 64 lanes — pure VALU (DPP)
      float sc = L;
      sc += W1 * dppf<0x111, 0xF>(sc);   // row_shr:1
      sc += W2 * dppf<0x112, 0xF>(sc);   // row_shr:2
      sc += W4 * dppf<0x114, 0xF>(sc);   // row_shr:4
      sc += W8 * dppf<0x118, 0xF>(sc);   // row_shr:8
      sc += F1 * dppf<0x142, 0xA>(sc);   // row_bcast15 → rows 1,3
      sc += F2 * dppf<0x143, 0xC>(sc);   // row_bcast31 → rows 2,3

      // segment total (lane 63) — off the per-segment chain, feeds carry only
      const float Stot = __builtin_bit_cast(float,
          __builtin_amdgcn_readlane(__builtin_bit_cast(int, sc), 63));
      // exclusive prefix: wave-wide shift right by 1 (lane0 → 0)
      const float e = dppf<0x138, 0xF>(sc);   // wf_sr1

      // replay exact reference op order over the lane's 4 elements
      float acc = e + Dlane * carry;
      f32x4 yv;
      acc = w * xv[0] + d * acc; yv[0] = acc;
      acc = w * xv[1] + d * acc; yv[1] = acc;
      acc = w * xv[2] + d * acc; yv[2] = acc;
      acc = w * xv[3] + d * acc; yv[3] = acc;

      if (s >= store_from) {
        if (s < 62) {
          *(f32x4*)(yr + s * 256 + lane * 4) = yv;
        } else if (s == 62 && lane < 32) {
          *(f32x4*)(yr + s * 256 + lane * 4) = yv;
        }
      }

      // serial carry chain: ONE fma per segment
      carry = Stot + D256 * carry;
    }
  }
}

extern "C" void kernel_launch(void* const* d_in, const int* in_sizes, int n_in,
                              void* d_out, int out_size, void* d_ws, size_t ws_size,
                              hipStream_t stream) {
  const float* x   = (const float*)d_in[0];
  const float* wts = (const float*)d_in[1];
  float* y         = (float*)d_out;
  ema_kernel<<<NROWS * 2, 64, 0, stream>>>(x, wts, y);
}